// Round 3
// baseline (11833.353 us; speedup 1.0000x reference)
//
#include <hip/hip_runtime.h>
#include <hip/hip_bf16.h>

#define N_NODES 50000
#define N_EDGES 800000
#define F_NODE  1363
#define F_STRUCT 83
#define F_ESM   1280
#define H1      128
#define H2      64
#define TE      32   // edges per block
#define TN      32   // nodes per block

__device__ __forceinline__ float silu_f(float x) { return x / (1.f + __expf(-x)); }
__device__ __forceinline__ float sigm_f(float x) { return 1.f / (1.f + __expf(-x)); }

// ---------------------------------------------------------------- zero-fill (replaces hipMemsetAsync)
__global__ void k_zero(float4* __restrict__ p, int n4) {
    int i = blockIdx.x * 256 + threadIdx.x;
    if (i < n4) p[i] = make_float4(0.f, 0.f, 0.f, 0.f);
}

// ---------------------------------------------------------------- h = h0 @ emb_w + emb_b
__global__ __launch_bounds__(H1) void k_emb(const float* __restrict__ na,
                                            const float* __restrict__ w,
                                            const float* __restrict__ b,
                                            float* __restrict__ h) {
    __shared__ float s0[F_STRUCT];
    int n = blockIdx.x, tid = threadIdx.x;
    if (tid < F_STRUCT) s0[tid] = na[n * F_NODE + tid];
    __syncthreads();
    float acc = b[tid];
    for (int k = 0; k < F_STRUCT; ++k)
        acc = fmaf(s0[k], w[k * H1 + tid], acc);
    h[n * H1 + tid] = acc;
}

// ---------------------------------------------------------------- edge MLP + attention + scatter
// 32 edges/block, 128 threads. Each thread = one output channel, 32 edge accumulators.
// radial computed on the fly from coords (no workspace array).
__global__ __launch_bounds__(128) void k_edge(
    const float* __restrict__ h, const int* __restrict__ ei,
    const float* __restrict__ coords, const float* __restrict__ ea,
    const float* __restrict__ ew1, const float* __restrict__ eb1,
    const float* __restrict__ ew2, const float* __restrict__ eb2,
    const float* __restrict__ aw,  const float* __restrict__ ab,
    float* __restrict__ agg) {
    __shared__ float s_in[TE][260];   // 258 padded to 260 (16B-aligned rows)
    __shared__ float s_m[TE][132];    // 128 padded to 132
    __shared__ float s_att[TE];
    __shared__ float s_aw[H1];
    __shared__ int   s_rc[2][TE];
    int tid = threadIdx.x;
    int e0  = blockIdx.x * TE;

    if (tid < TE) { s_rc[0][tid] = ei[e0 + tid]; s_rc[1][tid] = ei[N_EDGES + e0 + tid]; }
    s_aw[tid] = aw[tid];
    __syncthreads();

    // gather edge_in = [h[row], h[col], radial, ea]
    #pragma unroll 4
    for (int e = 0; e < TE; ++e) {
        int r = s_rc[0][e], c = s_rc[1][e];
        s_in[e][tid]      = h[r * H1 + tid];
        s_in[e][H1 + tid] = h[c * H1 + tid];
    }
    if (tid < TE) {
        int r = s_rc[0][tid], c = s_rc[1][tid];
        float dx = coords[r*3+0] - coords[c*3+0];
        float dy = coords[r*3+1] - coords[c*3+1];
        float dz = coords[r*3+2] - coords[c*3+2];
        s_in[tid][256] = dx*dx + dy*dy + dz*dz;
        s_in[tid][257] = ea[e0 + tid];
    }
    __syncthreads();

    // matvec1: 258 -> 128
    float acc[TE];
    {
        float bb = eb1[tid];
        #pragma unroll
        for (int e = 0; e < TE; ++e) acc[e] = bb;
    }
    for (int k = 0; k < 256; k += 4) {
        float w0 = ew1[(k+0)*H1 + tid];
        float w1 = ew1[(k+1)*H1 + tid];
        float w2 = ew1[(k+2)*H1 + tid];
        float w3 = ew1[(k+3)*H1 + tid];
        #pragma unroll
        for (int e = 0; e < TE; ++e) {
            const float4 x = *(const float4*)&s_in[e][k];
            acc[e] = fmaf(x.x, w0, acc[e]);
            acc[e] = fmaf(x.y, w1, acc[e]);
            acc[e] = fmaf(x.z, w2, acc[e]);
            acc[e] = fmaf(x.w, w3, acc[e]);
        }
    }
    {
        float w0 = ew1[256*H1 + tid];
        float w1 = ew1[257*H1 + tid];
        #pragma unroll
        for (int e = 0; e < TE; ++e) {
            acc[e] = fmaf(s_in[e][256], w0, acc[e]);
            acc[e] = fmaf(s_in[e][257], w1, acc[e]);
        }
    }
    #pragma unroll
    for (int e = 0; e < TE; ++e) s_m[e][tid] = silu_f(acc[e]);
    __syncthreads();

    // matvec2: 128 -> 128
    {
        float bb = eb2[tid];
        #pragma unroll
        for (int e = 0; e < TE; ++e) acc[e] = bb;
    }
    for (int k = 0; k < H1; k += 4) {
        float w0 = ew2[(k+0)*H1 + tid];
        float w1 = ew2[(k+1)*H1 + tid];
        float w2 = ew2[(k+2)*H1 + tid];
        float w3 = ew2[(k+3)*H1 + tid];
        #pragma unroll
        for (int e = 0; e < TE; ++e) {
            const float4 x = *(const float4*)&s_m[e][k];
            acc[e] = fmaf(x.x, w0, acc[e]);
            acc[e] = fmaf(x.y, w1, acc[e]);
            acc[e] = fmaf(x.z, w2, acc[e]);
            acc[e] = fmaf(x.w, w3, acc[e]);
        }
    }
    __syncthreads();                 // matvec2 reads of s_m done before overwrite
    #pragma unroll
    for (int e = 0; e < TE; ++e) s_m[e][tid] = silu_f(acc[e]);
    __syncthreads();

    // attention gate: sigmoid(m @ aw + ab), one thread per edge
    if (tid < TE) {
        float s = 0.f;
        for (int j = 0; j < H1; ++j) s = fmaf(s_m[tid][j], s_aw[j], s);
        s_att[tid] = sigm_f(s + ab[0]);
    }
    __syncthreads();

    // scatter-add to agg[row]
    #pragma unroll 4
    for (int e = 0; e < TE; ++e) {
        int r = s_rc[0][e];
        atomicAdd(&agg[r * H1 + tid], s_m[e][tid] * s_att[e]);
    }
}

// ---------------------------------------------------------------- node update (residual MLP)
__global__ __launch_bounds__(128) void k_node(
    const float* __restrict__ na, const float* __restrict__ agg,
    const float* __restrict__ nw1, const float* __restrict__ nb1,
    const float* __restrict__ nw2, const float* __restrict__ nb2,
    float* __restrict__ h) {
    __shared__ float s_in[TN][340];   // 339 padded to 340
    __shared__ float s_h[TN][132];
    int tid = threadIdx.x;
    int n0  = blockIdx.x * TN;

    #pragma unroll 4
    for (int e = 0; e < TN; ++e) {
        int n = n0 + e;
        if (n < N_NODES) {
            s_in[e][tid]        = h[n * H1 + tid];
            s_in[e][H1 + tid]   = agg[n * H1 + tid];
            if (tid < F_STRUCT) s_in[e][2*H1 + tid] = na[n * F_NODE + tid];
        } else {
            s_in[e][tid] = 0.f; s_in[e][H1 + tid] = 0.f;
            if (tid < F_STRUCT) s_in[e][2*H1 + tid] = 0.f;
        }
    }
    __syncthreads();

    float acc[TN];
    {
        float bb = nb1[tid];
        #pragma unroll
        for (int e = 0; e < TN; ++e) acc[e] = bb;
    }
    for (int k = 0; k < 336; k += 4) {
        float w0 = nw1[(k+0)*H1 + tid];
        float w1 = nw1[(k+1)*H1 + tid];
        float w2 = nw1[(k+2)*H1 + tid];
        float w3 = nw1[(k+3)*H1 + tid];
        #pragma unroll
        for (int e = 0; e < TN; ++e) {
            const float4 x = *(const float4*)&s_in[e][k];
            acc[e] = fmaf(x.x, w0, acc[e]);
            acc[e] = fmaf(x.y, w1, acc[e]);
            acc[e] = fmaf(x.z, w2, acc[e]);
            acc[e] = fmaf(x.w, w3, acc[e]);
        }
    }
    {
        float w0 = nw1[336*H1 + tid];
        float w1 = nw1[337*H1 + tid];
        float w2 = nw1[338*H1 + tid];
        #pragma unroll
        for (int e = 0; e < TN; ++e) {
            acc[e] = fmaf(s_in[e][336], w0, acc[e]);
            acc[e] = fmaf(s_in[e][337], w1, acc[e]);
            acc[e] = fmaf(s_in[e][338], w2, acc[e]);
        }
    }
    #pragma unroll
    for (int e = 0; e < TN; ++e) s_h[e][tid] = silu_f(acc[e]);
    __syncthreads();

    {
        float bb = nb2[tid];
        #pragma unroll
        for (int e = 0; e < TN; ++e) acc[e] = bb;
    }
    for (int k = 0; k < H1; k += 4) {
        float w0 = nw2[(k+0)*H1 + tid];
        float w1 = nw2[(k+1)*H1 + tid];
        float w2 = nw2[(k+2)*H1 + tid];
        float w3 = nw2[(k+3)*H1 + tid];
        #pragma unroll
        for (int e = 0; e < TN; ++e) {
            const float4 x = *(const float4*)&s_h[e][k];
            acc[e] = fmaf(x.x, w0, acc[e]);
            acc[e] = fmaf(x.y, w1, acc[e]);
            acc[e] = fmaf(x.z, w2, acc[e]);
            acc[e] = fmaf(x.w, w3, acc[e]);
        }
    }
    #pragma unroll 4
    for (int e = 0; e < TN; ++e) {
        int n = n0 + e;
        if (n < N_NODES) h[n * H1 + tid] = s_in[e][tid] + acc[e];  // residual
    }
}

// ---------------------------------------------------------------- decoder: h -> silu -> h
__global__ __launch_bounds__(128) void k_dec(
    const float* __restrict__ h,
    const float* __restrict__ w1, const float* __restrict__ b1,
    const float* __restrict__ w2, const float* __restrict__ b2,
    float* __restrict__ hdec) {
    __shared__ float s_in[TN][132];
    __shared__ float s_h[TN][132];
    int tid = threadIdx.x;
    int n0  = blockIdx.x * TN;

    #pragma unroll 4
    for (int e = 0; e < TN; ++e) {
        int n = n0 + e;
        s_in[e][tid] = (n < N_NODES) ? h[n * H1 + tid] : 0.f;
    }
    __syncthreads();

    float acc[TN];
    {
        float bb = b1[tid];
        #pragma unroll
        for (int e = 0; e < TN; ++e) acc[e] = bb;
    }
    for (int k = 0; k < H1; k += 4) {
        float w0  = w1[(k+0)*H1 + tid];
        float w1_ = w1[(k+1)*H1 + tid];
        float w2_ = w1[(k+2)*H1 + tid];
        float w3  = w1[(k+3)*H1 + tid];
        #pragma unroll
        for (int e = 0; e < TN; ++e) {
            const float4 x = *(const float4*)&s_in[e][k];
            acc[e] = fmaf(x.x, w0, acc[e]);
            acc[e] = fmaf(x.y, w1_, acc[e]);
            acc[e] = fmaf(x.z, w2_, acc[e]);
            acc[e] = fmaf(x.w, w3, acc[e]);
        }
    }
    #pragma unroll
    for (int e = 0; e < TN; ++e) s_h[e][tid] = silu_f(acc[e]);
    __syncthreads();

    {
        float bb = b2[tid];
        #pragma unroll
        for (int e = 0; e < TN; ++e) acc[e] = bb;
    }
    for (int k = 0; k < H1; k += 4) {
        float w0  = w2[(k+0)*H1 + tid];
        float w1_ = w2[(k+1)*H1 + tid];
        float w2_ = w2[(k+2)*H1 + tid];
        float w3  = w2[(k+3)*H1 + tid];
        #pragma unroll
        for (int e = 0; e < TN; ++e) {
            const float4 x = *(const float4*)&s_h[e][k];
            acc[e] = fmaf(x.x, w0, acc[e]);
            acc[e] = fmaf(x.y, w1_, acc[e]);
            acc[e] = fmaf(x.z, w2_, acc[e]);
            acc[e] = fmaf(x.w, w3, acc[e]);
        }
    }
    #pragma unroll 4
    for (int e = 0; e < TN; ++e) {
        int n = n0 + e;
        if (n < N_NODES) hdec[n * H1 + tid] = acc[e];
    }
}

// ---------------------------------------------------------------- ESM FFNN: 1280 -> 256(relu) -> 64(relu)
__global__ __launch_bounds__(256) void k_ffnn(
    const float* __restrict__ na,
    const float* __restrict__ w1, const float* __restrict__ b1,
    const float* __restrict__ w2, const float* __restrict__ b2,
    float* __restrict__ esm) {
    __shared__ float s_in[TN][132];   // 128-wide k tile
    __shared__ float s_h[TN][260];    // 256 hidden
    int tid = threadIdx.x;
    int n0  = blockIdx.x * TN;
    int half = tid >> 7;              // 0/1
    int lane = tid & 127;

    float acc[TN];
    {
        float bb = b1[tid];
        #pragma unroll
        for (int e = 0; e < TN; ++e) acc[e] = bb;
    }
    for (int kt = 0; kt < 10; ++kt) {
        __syncthreads();
        #pragma unroll 4
        for (int e = half; e < TN; e += 2) {
            int n = n0 + e;
            s_in[e][lane] = (n < N_NODES) ? na[n * F_NODE + F_STRUCT + kt*128 + lane] : 0.f;
        }
        __syncthreads();
        for (int k = 0; k < 128; k += 4) {
            float w0  = w1[(kt*128 + k + 0)*256 + tid];
            float w1_ = w1[(kt*128 + k + 1)*256 + tid];
            float w2_ = w1[(kt*128 + k + 2)*256 + tid];
            float w3  = w1[(kt*128 + k + 3)*256 + tid];
            #pragma unroll
            for (int e = 0; e < TN; ++e) {
                const float4 x = *(const float4*)&s_in[e][k];
                acc[e] = fmaf(x.x, w0, acc[e]);
                acc[e] = fmaf(x.y, w1_, acc[e]);
                acc[e] = fmaf(x.z, w2_, acc[e]);
                acc[e] = fmaf(x.w, w3, acc[e]);
            }
        }
    }
    #pragma unroll
    for (int e = 0; e < TN; ++e) s_h[e][tid] = fmaxf(acc[e], 0.f);
    __syncthreads();

    // layer 2: 256 -> 64. thread = (q = tid>>6 node-octet, j = tid&63 output)
    int q = tid >> 6, j = tid & 63;
    float acc2[8];
    {
        float bb = b2[j];
        #pragma unroll
        for (int ee = 0; ee < 8; ++ee) acc2[ee] = bb;
    }
    for (int k = 0; k < 256; k += 4) {
        float w0  = w2[(k+0)*H2 + j];
        float w1_ = w2[(k+1)*H2 + j];
        float w2_ = w2[(k+2)*H2 + j];
        float w3  = w2[(k+3)*H2 + j];
        #pragma unroll
        for (int ee = 0; ee < 8; ++ee) {
            const float4 x = *(const float4*)&s_h[q*8 + ee][k];
            acc2[ee] = fmaf(x.x, w0, acc2[ee]);
            acc2[ee] = fmaf(x.y, w1_, acc2[ee]);
            acc2[ee] = fmaf(x.z, w2_, acc2[ee]);
            acc2[ee] = fmaf(x.w, w3, acc2[ee]);
        }
    }
    #pragma unroll
    for (int ee = 0; ee < 8; ++ee) {
        int n = n0 + q*8 + ee;
        if (n < N_NODES) esm[n * H2 + j] = fmaxf(acc2[ee], 0.f);
    }
}

// ---------------------------------------------------------------- last head: 192 -> silu -> 1 -> sigmoid
__global__ __launch_bounds__(192) void k_last(
    const float* __restrict__ hdec, const float* __restrict__ esm,
    const float* __restrict__ w1, const float* __restrict__ b1,
    const float* __restrict__ w2, const float* __restrict__ b2,
    float* __restrict__ out) {
    __shared__ float s_in[TN][196];   // 192 padded
    __shared__ float s_h[TN][196];
    __shared__ float s_w2[192];
    int tid = threadIdx.x;
    int n0  = blockIdx.x * TN;

    s_w2[tid] = w2[tid];
    #pragma unroll 4
    for (int e = 0; e < TN; ++e) {
        int n = n0 + e;
        if (n < N_NODES) {
            s_in[e][tid] = (tid < H1) ? hdec[n * H1 + tid] : esm[n * H2 + (tid - H1)];
        } else {
            s_in[e][tid] = 0.f;
        }
    }
    __syncthreads();

    float acc[TN];
    {
        float bb = b1[tid];
        #pragma unroll
        for (int e = 0; e < TN; ++e) acc[e] = bb;
    }
    for (int k = 0; k < 192; k += 4) {
        float w0  = w1[(k+0)*192 + tid];
        float w1_ = w1[(k+1)*192 + tid];
        float w2_ = w1[(k+2)*192 + tid];
        float w3  = w1[(k+3)*192 + tid];
        #pragma unroll
        for (int e = 0; e < TN; ++e) {
            const float4 x = *(const float4*)&s_in[e][k];
            acc[e] = fmaf(x.x, w0, acc[e]);
            acc[e] = fmaf(x.y, w1_, acc[e]);
            acc[e] = fmaf(x.z, w2_, acc[e]);
            acc[e] = fmaf(x.w, w3, acc[e]);
        }
    }
    #pragma unroll
    for (int e = 0; e < TN; ++e) s_h[e][tid] = silu_f(acc[e]);
    __syncthreads();

    if (tid < TN) {
        int n = n0 + tid;
        if (n < N_NODES) {
            float s = 0.f;
            for (int j = 0; j < 192; ++j) s = fmaf(s_h[tid][j], s_w2[j], s);
            out[n] = sigm_f(s + b2[0]);
        }
    }
}

// ----------------------------------------------------------------
extern "C" void kernel_launch(void* const* d_in, const int* in_sizes, int n_in,
                              void* d_out, int out_size, void* d_ws, size_t ws_size,
                              hipStream_t stream) {
    const float* na      = (const float*)d_in[0];
    const float* coords  = (const float*)d_in[1];
    const int*   ei      = (const int*)  d_in[2];
    const float* ea      = (const float*)d_in[3];
    const float* emb_w   = (const float*)d_in[4];
    const float* emb_b   = (const float*)d_in[5];
    const float* edge_w1 = (const float*)d_in[6];
    const float* edge_b1 = (const float*)d_in[7];
    const float* edge_w2 = (const float*)d_in[8];
    const float* edge_b2 = (const float*)d_in[9];
    const float* att_w   = (const float*)d_in[10];
    const float* att_b   = (const float*)d_in[11];
    const float* node_w1 = (const float*)d_in[12];
    const float* node_b1 = (const float*)d_in[13];
    const float* node_w2 = (const float*)d_in[14];
    const float* node_b2 = (const float*)d_in[15];
    const float* dec_w1  = (const float*)d_in[16];
    const float* dec_b1  = (const float*)d_in[17];
    const float* dec_w2  = (const float*)d_in[18];
    const float* dec_b2  = (const float*)d_in[19];
    const float* ffnn_w1 = (const float*)d_in[20];
    const float* ffnn_b1 = (const float*)d_in[21];
    const float* ffnn_w2 = (const float*)d_in[22];
    const float* ffnn_b2 = (const float*)d_in[23];
    const float* last_w1 = (const float*)d_in[24];
    const float* last_b1 = (const float*)d_in[25];
    const float* last_w2 = (const float*)d_in[26];
    const float* last_b2 = (const float*)d_in[27];

    // workspace layout (floats): h | agg  — exactly 2*N*H1*4 = 51.2 MB.
    // hdec reuses agg after the last GNN layer; esm reuses h after the decoder.
    const size_t need = 2ull * N_NODES * H1 * sizeof(float);
    if (ws_size < need) return;   // diagnostic guard: out stays zeroed -> absmax ~0.625

    float* h      = (float*)d_ws;
    float* agg    = h + (size_t)N_NODES * H1;
    float* hdec   = agg;   // reused after last GNN layer
    float* esm    = h;     // reused after decoder
    float* out    = (float*)d_out;

    int nblk = (N_NODES + TN - 1) / TN;
    int n4   = N_NODES * H1 / 4;

    k_emb<<<N_NODES, H1, 0, stream>>>(na, emb_w, emb_b, h);

    for (int i = 0; i < 4; ++i) {
        k_zero<<<(n4 + 255) / 256, 256, 0, stream>>>((float4*)agg, n4);
        k_edge<<<N_EDGES / TE, 128, 0, stream>>>(
            h, ei, coords, ea,
            edge_w1 + (size_t)i * 258 * H1, edge_b1 + i * H1,
            edge_w2 + (size_t)i * H1 * H1,  edge_b2 + i * H1,
            att_w + i * H1, att_b + i, agg);
        k_node<<<nblk, 128, 0, stream>>>(
            na, agg,
            node_w1 + (size_t)i * 339 * H1, node_b1 + i * H1,
            node_w2 + (size_t)i * H1 * H1,  node_b2 + i * H1, h);
    }

    k_dec<<<nblk, 128, 0, stream>>>(h, dec_w1, dec_b1, dec_w2, dec_b2, hdec);
    k_ffnn<<<nblk, 256, 0, stream>>>(na, ffnn_w1, ffnn_b1, ffnn_w2, ffnn_b2, esm);
    k_last<<<nblk, 192, 0, stream>>>(hdec, esm, last_w1, last_b1, last_w2, last_b2, out);
}

// Round 4
// 4997.394 us; speedup vs baseline: 2.3679x; 2.3679x over previous
//
#include <hip/hip_runtime.h>
#include <hip/hip_bf16.h>

#define N_NODES 50000
#define N_EDGES 800000
#define F_NODE  1363
#define F_STRUCT 83
#define F_ESM   1280
#define H1      128
#define H2      64
#define TN      32    // nodes per block (non-edge kernels)

// edge-kernel tiling
#define TEM      64                 // edges per tile
#define NTILES   (N_EDGES / TEM)    // 12500
#define GRID_E   512                // persistent blocks (2 per CU)
#define SIN_LD   296                // 288 + 8 pad: stride 148 dwords -> 2-way (free) LDS pattern
#define SM_LD    136                // 128 + 8 pad: stride 68 dwords -> 2-way (free)

typedef __attribute__((ext_vector_type(8))) short short8;   // 8 x bf16 (4 VGPRs)
typedef __attribute__((ext_vector_type(4))) float floatx4;  // MFMA accumulator

__device__ __forceinline__ float silu_f(float x) { return x / (1.f + __expf(-x)); }
__device__ __forceinline__ float sigm_f(float x) { return 1.f / (1.f + __expf(-x)); }

// fp32 -> bf16 bits, round-to-nearest-even (finite inputs only)
__device__ __forceinline__ unsigned short f2bf(float f) {
    unsigned int u = __float_as_uint(f);
    unsigned int r = (u + 0x7FFFu + ((u >> 16) & 1u)) >> 16;
    return (unsigned short)r;
}
// packed bf16x2 -> floats
__device__ __forceinline__ float bflo(unsigned int u) { return __uint_as_float(u << 16); }
__device__ __forceinline__ float bfhi(unsigned int u) { return __uint_as_float(u & 0xFFFF0000u); }

// ---------------------------------------------------------------- zero-fill
__global__ void k_zero(float4* __restrict__ p, int n4) {
    int i = blockIdx.x * 256 + threadIdx.x;
    if (i < n4) p[i] = make_float4(0.f, 0.f, 0.f, 0.f);
}

// ---------------------------------------------------------------- h = h0 @ emb_w + emb_b
__global__ __launch_bounds__(H1) void k_emb(const float* __restrict__ na,
                                            const float* __restrict__ w,
                                            const float* __restrict__ b,
                                            float* __restrict__ h) {
    __shared__ float s0[F_STRUCT];
    int n = blockIdx.x, tid = threadIdx.x;
    if (tid < F_STRUCT) s0[tid] = na[n * F_NODE + tid];
    __syncthreads();
    float acc = b[tid];
    for (int k = 0; k < F_STRUCT; ++k)
        acc = fmaf(s0[k], w[k * H1 + tid], acc);
    h[n * H1 + tid] = acc;
}

// ---------------------------------------------------------------- edge MLP via MFMA bf16
// Persistent blocks: weights held in registers as B-fragments; grid-stride over
// 12500 tiles of 64 edges. GEMM1: [64x288]@[288x128]; GEMM2: [64x128]@[128x128].
// mfma_f32_16x16x32_bf16 layouts (verified, learn_hip m89/m91/m120):
//   A[m = lane&15][k = (lane>>4)*8 + j]   (short8, j=0..7)
//   B[k = (lane>>4)*8 + j][n = lane&15]
//   D: col = lane&15, row = (lane>>4)*4 + reg
__global__ __launch_bounds__(256, 2) void k_edge_mfma(
    const float* __restrict__ h, const int* __restrict__ ei,
    const float* __restrict__ coords, const float* __restrict__ ea,
    const float* __restrict__ ew1, const float* __restrict__ eb1,
    const float* __restrict__ ew2, const float* __restrict__ eb2,
    const float* __restrict__ aw,  const float* __restrict__ ab,
    float* __restrict__ agg) {

    __shared__ unsigned short sIn[TEM * SIN_LD];   // 37888 B
    __shared__ unsigned short sM [TEM * SM_LD];    // 17408 B
    __shared__ float s_aw[H1];
    __shared__ float s_p[4][TEM];
    __shared__ float s_att[TEM];
    __shared__ int   s_r[TEM], s_c[TEM];

    const int tid  = threadIdx.x;
    const int wv   = tid >> 6;
    const int lane = tid & 63;
    const int l16  = lane & 15;
    const int quad = lane >> 4;

    if (tid < H1) s_aw[tid] = aw[tid];
    // zero the pad cols [258..295] once; never rewritten (MFMA must not see NaN garbage)
    for (int i = tid; i < TEM * (SIN_LD - 258); i += 256) {
        int r = i / (SIN_LD - 258), c = i % (SIN_LD - 258);
        sIn[r * SIN_LD + 258 + c] = 0;
    }

    // ---- load B-fragments (weights) once per block into registers
    short8 B1[2][9];   // GEMM1: K=288 (zero-padded past 258), N-slice per (wv,s)
    short8 B2[2][4];   // GEMM2: K=128
    float  bias1[2], bias2[2];
    #pragma unroll
    for (int s = 0; s < 2; ++s) {
        const int n = (2 * wv + s) * 16 + l16;
        bias1[s] = eb1[n];
        bias2[s] = eb2[n];
        #pragma unroll
        for (int kt = 0; kt < 9; ++kt) {
            short8 f;
            #pragma unroll
            for (int j = 0; j < 8; ++j) {
                int k = kt * 32 + quad * 8 + j;
                float v = (k < 258) ? ew1[k * H1 + n] : 0.f;
                f[j] = (short)f2bf(v);
            }
            B1[s][kt] = f;
        }
        #pragma unroll
        for (int kt = 0; kt < 4; ++kt) {
            short8 f;
            #pragma unroll
            for (int j = 0; j < 8; ++j) {
                int k = kt * 32 + quad * 8 + j;
                f[j] = (short)f2bf(ew2[k * H1 + n]);
            }
            B2[s][kt] = f;
        }
    }
    const float ab0 = ab[0];

    for (int t = blockIdx.x; t < NTILES; t += GRID_E) {
        const int e0 = t * TEM;
        __syncthreads();   // previous iteration fully done with shared state

        if (tid < TEM) {
            int r = ei[e0 + tid], c = ei[N_EDGES + e0 + tid];
            s_r[tid] = r; s_c[tid] = c;
            float dx = coords[r*3+0] - coords[c*3+0];
            float dy = coords[r*3+1] - coords[c*3+1];
            float dz = coords[r*3+2] - coords[c*3+2];
            sIn[tid * SIN_LD + 256] = f2bf(dx*dx + dy*dy + dz*dz);
            sIn[tid * SIN_LD + 257] = f2bf(ea[e0 + tid]);
        }
        __syncthreads();

        // gather: edge_in[e][0:128]=h[row], [128:256]=h[col], fp32 -> bf16
        #pragma unroll
        for (int i = 0; i < 16; ++i) {
            int idx  = i * 256 + tid;
            int e    = idx >> 6;
            int part = idx & 63;
            const float* src = (part < 32)
                ? (h + (size_t)s_r[e] * H1 + part * 4)
                : (h + (size_t)s_c[e] * H1 + (part - 32) * 4);
            float4 x = *(const float4*)src;
            unsigned int lo = (unsigned)f2bf(x.x) | ((unsigned)f2bf(x.y) << 16);
            unsigned int hi = (unsigned)f2bf(x.z) | ((unsigned)f2bf(x.w) << 16);
            *(uint2*)&sIn[e * SIN_LD + part * 4] = make_uint2(lo, hi);
        }
        __syncthreads();

        // ---- GEMM1: acc[mt][s] = edge_in @ ew1 + b1
        floatx4 acc[4][2];
        #pragma unroll
        for (int mt = 0; mt < 4; ++mt)
            #pragma unroll
            for (int s = 0; s < 2; ++s)
                acc[mt][s] = (floatx4){bias1[s], bias1[s], bias1[s], bias1[s]};
        #pragma unroll
        for (int kt = 0; kt < 9; ++kt) {
            short8 A[4];
            #pragma unroll
            for (int mt = 0; mt < 4; ++mt)
                A[mt] = *(const short8*)&sIn[(mt*16 + l16) * SIN_LD + kt*32 + quad*8];
            #pragma unroll
            for (int mt = 0; mt < 4; ++mt)
                #pragma unroll
                for (int s = 0; s < 2; ++s)
                    acc[mt][s] = __builtin_amdgcn_mfma_f32_16x16x32_bf16(
                        A[mt], B1[s][kt], acc[mt][s], 0, 0, 0);
        }
        // silu -> sM (bf16 A-operand of GEMM2)
        #pragma unroll
        for (int mt = 0; mt < 4; ++mt)
            #pragma unroll
            for (int s = 0; s < 2; ++s)
                #pragma unroll
                for (int r = 0; r < 4; ++r) {
                    int row = mt*16 + quad*4 + r;
                    int col = (2*wv + s)*16 + l16;
                    sM[row * SM_LD + col] = f2bf(silu_f(acc[mt][s][r]));
                }
        __syncthreads();

        // attention partials (VALU) — independent of GEMM2 (MFMA), both read sM
        {
            int e = tid & 63, part = tid >> 6;
            const uint2* pm  = (const uint2*)&sM[e * SM_LD + part * 32];
            const float* paw = &s_aw[part * 32];
            float ssum = 0.f;
            #pragma unroll
            for (int j = 0; j < 8; ++j) {
                uint2 u = pm[j];
                ssum = fmaf(bflo(u.x), paw[4*j+0], ssum);
                ssum = fmaf(bfhi(u.x), paw[4*j+1], ssum);
                ssum = fmaf(bflo(u.y), paw[4*j+2], ssum);
                ssum = fmaf(bfhi(u.y), paw[4*j+3], ssum);
            }
            s_p[part][e] = ssum;
        }

        // ---- GEMM2: acc2[mt][s] = m @ ew2 + b2
        floatx4 acc2[4][2];
        #pragma unroll
        for (int mt = 0; mt < 4; ++mt)
            #pragma unroll
            for (int s = 0; s < 2; ++s)
                acc2[mt][s] = (floatx4){bias2[s], bias2[s], bias2[s], bias2[s]};
        #pragma unroll
        for (int kt = 0; kt < 4; ++kt) {
            short8 A[4];
            #pragma unroll
            for (int mt = 0; mt < 4; ++mt)
                A[mt] = *(const short8*)&sM[(mt*16 + l16) * SM_LD + kt*32 + quad*8];
            #pragma unroll
            for (int mt = 0; mt < 4; ++mt)
                #pragma unroll
                for (int s = 0; s < 2; ++s)
                    acc2[mt][s] = __builtin_amdgcn_mfma_f32_16x16x32_bf16(
                        A[mt], B2[s][kt], acc2[mt][s], 0, 0, 0);
        }
        __syncthreads();

        if (tid < TEM)
            s_att[tid] = sigm_f(s_p[0][tid] + s_p[1][tid] + s_p[2][tid] + s_p[3][tid] + ab0);
        __syncthreads();

        // scatter: agg[row_node] += silu(m2) * att   (fused from accumulators)
        #pragma unroll
        for (int mt = 0; mt < 4; ++mt)
            #pragma unroll
            for (int s = 0; s < 2; ++s)
                #pragma unroll
                for (int r = 0; r < 4; ++r) {
                    int edge = mt*16 + quad*4 + r;
                    int col  = (2*wv + s)*16 + l16;
                    float v  = silu_f(acc2[mt][s][r]) * s_att[edge];
                    atomicAdd(&agg[(size_t)s_r[edge] * H1 + col], v);
                }
    }
}

// ---------------------------------------------------------------- node update (residual MLP)
__global__ __launch_bounds__(128) void k_node(
    const float* __restrict__ na, const float* __restrict__ agg,
    const float* __restrict__ nw1, const float* __restrict__ nb1,
    const float* __restrict__ nw2, const float* __restrict__ nb2,
    float* __restrict__ h) {
    __shared__ float s_in[TN][340];
    __shared__ float s_h[TN][132];
    int tid = threadIdx.x;
    int n0  = blockIdx.x * TN;

    #pragma unroll 4
    for (int e = 0; e < TN; ++e) {
        int n = n0 + e;
        if (n < N_NODES) {
            s_in[e][tid]        = h[n * H1 + tid];
            s_in[e][H1 + tid]   = agg[n * H1 + tid];
            if (tid < F_STRUCT) s_in[e][2*H1 + tid] = na[n * F_NODE + tid];
        } else {
            s_in[e][tid] = 0.f; s_in[e][H1 + tid] = 0.f;
            if (tid < F_STRUCT) s_in[e][2*H1 + tid] = 0.f;
        }
    }
    __syncthreads();

    float acc[TN];
    {
        float bb = nb1[tid];
        #pragma unroll
        for (int e = 0; e < TN; ++e) acc[e] = bb;
    }
    for (int k = 0; k < 336; k += 4) {
        float w0 = nw1[(k+0)*H1 + tid];
        float w1 = nw1[(k+1)*H1 + tid];
        float w2 = nw1[(k+2)*H1 + tid];
        float w3 = nw1[(k+3)*H1 + tid];
        #pragma unroll
        for (int e = 0; e < TN; ++e) {
            const float4 x = *(const float4*)&s_in[e][k];
            acc[e] = fmaf(x.x, w0, acc[e]);
            acc[e] = fmaf(x.y, w1, acc[e]);
            acc[e] = fmaf(x.z, w2, acc[e]);
            acc[e] = fmaf(x.w, w3, acc[e]);
        }
    }
    {
        float w0 = nw1[336*H1 + tid];
        float w1 = nw1[337*H1 + tid];
        float w2 = nw1[338*H1 + tid];
        #pragma unroll
        for (int e = 0; e < TN; ++e) {
            acc[e] = fmaf(s_in[e][336], w0, acc[e]);
            acc[e] = fmaf(s_in[e][337], w1, acc[e]);
            acc[e] = fmaf(s_in[e][338], w2, acc[e]);
        }
    }
    #pragma unroll
    for (int e = 0; e < TN; ++e) s_h[e][tid] = silu_f(acc[e]);
    __syncthreads();

    {
        float bb = nb2[tid];
        #pragma unroll
        for (int e = 0; e < TN; ++e) acc[e] = bb;
    }
    for (int k = 0; k < H1; k += 4) {
        float w0 = nw2[(k+0)*H1 + tid];
        float w1 = nw2[(k+1)*H1 + tid];
        float w2 = nw2[(k+2)*H1 + tid];
        float w3 = nw2[(k+3)*H1 + tid];
        #pragma unroll
        for (int e = 0; e < TN; ++e) {
            const float4 x = *(const float4*)&s_h[e][k];
            acc[e] = fmaf(x.x, w0, acc[e]);
            acc[e] = fmaf(x.y, w1, acc[e]);
            acc[e] = fmaf(x.z, w2, acc[e]);
            acc[e] = fmaf(x.w, w3, acc[e]);
        }
    }
    #pragma unroll 4
    for (int e = 0; e < TN; ++e) {
        int n = n0 + e;
        if (n < N_NODES) h[n * H1 + tid] = s_in[e][tid] + acc[e];
    }
}

// ---------------------------------------------------------------- decoder
__global__ __launch_bounds__(128) void k_dec(
    const float* __restrict__ h,
    const float* __restrict__ w1, const float* __restrict__ b1,
    const float* __restrict__ w2, const float* __restrict__ b2,
    float* __restrict__ hdec) {
    __shared__ float s_in[TN][132];
    __shared__ float s_h[TN][132];
    int tid = threadIdx.x;
    int n0  = blockIdx.x * TN;

    #pragma unroll 4
    for (int e = 0; e < TN; ++e) {
        int n = n0 + e;
        s_in[e][tid] = (n < N_NODES) ? h[n * H1 + tid] : 0.f;
    }
    __syncthreads();

    float acc[TN];
    {
        float bb = b1[tid];
        #pragma unroll
        for (int e = 0; e < TN; ++e) acc[e] = bb;
    }
    for (int k = 0; k < H1; k += 4) {
        float w0  = w1[(k+0)*H1 + tid];
        float w1_ = w1[(k+1)*H1 + tid];
        float w2_ = w1[(k+2)*H1 + tid];
        float w3  = w1[(k+3)*H1 + tid];
        #pragma unroll
        for (int e = 0; e < TN; ++e) {
            const float4 x = *(const float4*)&s_in[e][k];
            acc[e] = fmaf(x.x, w0, acc[e]);
            acc[e] = fmaf(x.y, w1_, acc[e]);
            acc[e] = fmaf(x.z, w2_, acc[e]);
            acc[e] = fmaf(x.w, w3, acc[e]);
        }
    }
    #pragma unroll
    for (int e = 0; e < TN; ++e) s_h[e][tid] = silu_f(acc[e]);
    __syncthreads();

    {
        float bb = b2[tid];
        #pragma unroll
        for (int e = 0; e < TN; ++e) acc[e] = bb;
    }
    for (int k = 0; k < H1; k += 4) {
        float w0  = w2[(k+0)*H1 + tid];
        float w1_ = w2[(k+1)*H1 + tid];
        float w2_ = w2[(k+2)*H1 + tid];
        float w3  = w2[(k+3)*H1 + tid];
        #pragma unroll
        for (int e = 0; e < TN; ++e) {
            const float4 x = *(const float4*)&s_h[e][k];
            acc[e] = fmaf(x.x, w0, acc[e]);
            acc[e] = fmaf(x.y, w1_, acc[e]);
            acc[e] = fmaf(x.z, w2_, acc[e]);
            acc[e] = fmaf(x.w, w3, acc[e]);
        }
    }
    #pragma unroll 4
    for (int e = 0; e < TN; ++e) {
        int n = n0 + e;
        if (n < N_NODES) hdec[n * H1 + tid] = acc[e];
    }
}

// ---------------------------------------------------------------- ESM FFNN: 1280 -> 256(relu) -> 64(relu)
__global__ __launch_bounds__(256) void k_ffnn(
    const float* __restrict__ na,
    const float* __restrict__ w1, const float* __restrict__ b1,
    const float* __restrict__ w2, const float* __restrict__ b2,
    float* __restrict__ esm) {
    __shared__ float s_in[TN][132];
    __shared__ float s_h[TN][260];
    int tid = threadIdx.x;
    int n0  = blockIdx.x * TN;
    int half = tid >> 7;
    int lane = tid & 127;

    float acc[TN];
    {
        float bb = b1[tid];
        #pragma unroll
        for (int e = 0; e < TN; ++e) acc[e] = bb;
    }
    for (int kt = 0; kt < 10; ++kt) {
        __syncthreads();
        #pragma unroll 4
        for (int e = half; e < TN; e += 2) {
            int n = n0 + e;
            s_in[e][lane] = (n < N_NODES) ? na[n * F_NODE + F_STRUCT + kt*128 + lane] : 0.f;
        }
        __syncthreads();
        for (int k = 0; k < 128; k += 4) {
            float w0  = w1[(kt*128 + k + 0)*256 + tid];
            float w1_ = w1[(kt*128 + k + 1)*256 + tid];
            float w2_ = w1[(kt*128 + k + 2)*256 + tid];
            float w3  = w1[(kt*128 + k + 3)*256 + tid];
            #pragma unroll
            for (int e = 0; e < TN; ++e) {
                const float4 x = *(const float4*)&s_in[e][k];
                acc[e] = fmaf(x.x, w0, acc[e]);
                acc[e] = fmaf(x.y, w1_, acc[e]);
                acc[e] = fmaf(x.z, w2_, acc[e]);
                acc[e] = fmaf(x.w, w3, acc[e]);
            }
        }
    }
    #pragma unroll
    for (int e = 0; e < TN; ++e) s_h[e][tid] = fmaxf(acc[e], 0.f);
    __syncthreads();

    int q = tid >> 6, j = tid & 63;
    float acc2[8];
    {
        float bb = b2[j];
        #pragma unroll
        for (int ee = 0; ee < 8; ++ee) acc2[ee] = bb;
    }
    for (int k = 0; k < 256; k += 4) {
        float w0  = w2[(k+0)*H2 + j];
        float w1_ = w2[(k+1)*H2 + j];
        float w2_ = w2[(k+2)*H2 + j];
        float w3  = w2[(k+3)*H2 + j];
        #pragma unroll
        for (int ee = 0; ee < 8; ++ee) {
            const float4 x = *(const float4*)&s_h[q*8 + ee][k];
            acc2[ee] = fmaf(x.x, w0, acc2[ee]);
            acc2[ee] = fmaf(x.y, w1_, acc2[ee]);
            acc2[ee] = fmaf(x.z, w2_, acc2[ee]);
            acc2[ee] = fmaf(x.w, w3, acc2[ee]);
        }
    }
    #pragma unroll
    for (int ee = 0; ee < 8; ++ee) {
        int n = n0 + q*8 + ee;
        if (n < N_NODES) esm[n * H2 + j] = fmaxf(acc2[ee], 0.f);
    }
}

// ---------------------------------------------------------------- last head
__global__ __launch_bounds__(192) void k_last(
    const float* __restrict__ hdec, const float* __restrict__ esm,
    const float* __restrict__ w1, const float* __restrict__ b1,
    const float* __restrict__ w2, const float* __restrict__ b2,
    float* __restrict__ out) {
    __shared__ float s_in[TN][196];
    __shared__ float s_h[TN][196];
    __shared__ float s_w2[192];
    int tid = threadIdx.x;
    int n0  = blockIdx.x * TN;

    s_w2[tid] = w2[tid];
    #pragma unroll 4
    for (int e = 0; e < TN; ++e) {
        int n = n0 + e;
        if (n < N_NODES) {
            s_in[e][tid] = (tid < H1) ? hdec[n * H1 + tid] : esm[n * H2 + (tid - H1)];
        } else {
            s_in[e][tid] = 0.f;
        }
    }
    __syncthreads();

    float acc[TN];
    {
        float bb = b1[tid];
        #pragma unroll
        for (int e = 0; e < TN; ++e) acc[e] = bb;
    }
    for (int k = 0; k < 192; k += 4) {
        float w0  = w1[(k+0)*192 + tid];
        float w1_ = w1[(k+1)*192 + tid];
        float w2_ = w1[(k+2)*192 + tid];
        float w3  = w1[(k+3)*192 + tid];
        #pragma unroll
        for (int e = 0; e < TN; ++e) {
            const float4 x = *(const float4*)&s_in[e][k];
            acc[e] = fmaf(x.x, w0, acc[e]);
            acc[e] = fmaf(x.y, w1_, acc[e]);
            acc[e] = fmaf(x.z, w2_, acc[e]);
            acc[e] = fmaf(x.w, w3, acc[e]);
        }
    }
    #pragma unroll
    for (int e = 0; e < TN; ++e) s_h[e][tid] = silu_f(acc[e]);
    __syncthreads();

    if (tid < TN) {
        int n = n0 + tid;
        if (n < N_NODES) {
            float s = 0.f;
            for (int j = 0; j < 192; ++j) s = fmaf(s_h[tid][j], s_w2[j], s);
            out[n] = sigm_f(s + b2[0]);
        }
    }
}

// ----------------------------------------------------------------
extern "C" void kernel_launch(void* const* d_in, const int* in_sizes, int n_in,
                              void* d_out, int out_size, void* d_ws, size_t ws_size,
                              hipStream_t stream) {
    const float* na      = (const float*)d_in[0];
    const float* coords  = (const float*)d_in[1];
    const int*   ei      = (const int*)  d_in[2];
    const float* ea      = (const float*)d_in[3];
    const float* emb_w   = (const float*)d_in[4];
    const float* emb_b   = (const float*)d_in[5];
    const float* edge_w1 = (const float*)d_in[6];
    const float* edge_b1 = (const float*)d_in[7];
    const float* edge_w2 = (const float*)d_in[8];
    const float* edge_b2 = (const float*)d_in[9];
    const float* att_w   = (const float*)d_in[10];
    const float* att_b   = (const float*)d_in[11];
    const float* node_w1 = (const float*)d_in[12];
    const float* node_b1 = (const float*)d_in[13];
    const float* node_w2 = (const float*)d_in[14];
    const float* node_b2 = (const float*)d_in[15];
    const float* dec_w1  = (const float*)d_in[16];
    const float* dec_b1  = (const float*)d_in[17];
    const float* dec_w2  = (const float*)d_in[18];
    const float* dec_b2  = (const float*)d_in[19];
    const float* ffnn_w1 = (const float*)d_in[20];
    const float* ffnn_b1 = (const float*)d_in[21];
    const float* ffnn_w2 = (const float*)d_in[22];
    const float* ffnn_b2 = (const float*)d_in[23];
    const float* last_w1 = (const float*)d_in[24];
    const float* last_b1 = (const float*)d_in[25];
    const float* last_w2 = (const float*)d_in[26];
    const float* last_b2 = (const float*)d_in[27];

    // workspace: h | agg = exactly 51.2 MB (ws_size is known to be < 54.4 MB — do not grow)
    const size_t need = 2ull * N_NODES * H1 * sizeof(float);
    if (ws_size < need) return;

    float* h    = (float*)d_ws;
    float* agg  = h + (size_t)N_NODES * H1;
    float* hdec = agg;
    float* esm  = h;
    float* out  = (float*)d_out;

    int nblk = (N_NODES + TN - 1) / TN;
    int n4   = N_NODES * H1 / 4;

    k_emb<<<N_NODES, H1, 0, stream>>>(na, emb_w, emb_b, h);

    for (int i = 0; i < 4; ++i) {
        k_zero<<<(n4 + 255) / 256, 256, 0, stream>>>((float4*)agg, n4);
        k_edge_mfma<<<GRID_E, 256, 0, stream>>>(
            h, ei, coords, ea,
            edge_w1 + (size_t)i * 258 * H1, edge_b1 + i * H1,
            edge_w2 + (size_t)i * H1 * H1,  edge_b2 + i * H1,
            att_w + i * H1, att_b + i, agg);
        k_node<<<nblk, 128, 0, stream>>>(
            na, agg,
            node_w1 + (size_t)i * 339 * H1, node_b1 + i * H1,
            node_w2 + (size_t)i * H1 * H1,  node_b2 + i * H1, h);
    }

    k_dec<<<nblk, 128, 0, stream>>>(h, dec_w1, dec_b1, dec_w2, dec_b2, hdec);
    k_ffnn<<<nblk, 256, 0, stream>>>(na, ffnn_w1, ffnn_b1, ffnn_w2, ffnn_b2, esm);
    k_last<<<nblk, 192, 0, stream>>>(hdec, esm, last_w1, last_b1, last_w2, last_b2, out);
}